// Round 7
// baseline (568.126 us; speedup 1.0000x reference)
//
#include <hip/hip_runtime.h>
#include <cstdint>
#include <cmath>

#define DEV static __device__ __forceinline__

typedef __attribute__((ext_vector_type(8))) short bf16x8;   // 8 bf16 in 4 VGPRs
typedef __attribute__((ext_vector_type(4))) float f32x4;    // MFMA accumulator

constexpr int B_  = 8;
constexpr int S_  = 2048;
constexpr int DIN = 1024;
constexpr int DH  = 128;
constexpr int M_  = B_ * S_;   // 16384 token rows

// ---------- bf16 helpers (manual, RNE) ----------
DEV uint16_t bf16_rne(float f) {
  uint32_t u = __float_as_uint(f);
  u += 0x7FFFu + ((u >> 16) & 1u);
  return (uint16_t)(u >> 16);
}
DEV float bf16_f32(uint16_t h) { return __uint_as_float(((uint32_t)h) << 16); }
DEV void split2(float f, uint16_t& h, uint16_t& l) {
  h = bf16_rne(f);
  l = bf16_rne(f - bf16_f32(h));   // exact residual, then round: ~2^-17 combined
}
DEV f32x4 mfma(bf16x8 a, bf16x8 b, f32x4 c) {
  return __builtin_amdgcn_mfma_f32_16x16x32_bf16(a, b, c, 0, 0, 0);
}
DEV bf16x8 ld8(const uint16_t* p) { return *reinterpret_cast<const bf16x8*>(p); }

// ---------- kernel 1: split x (f32 -> hi/lo bf16) ----------
__global__ __launch_bounds__(256) void k_split_x(const float* __restrict__ src,
                                                 uint16_t* __restrict__ hi,
                                                 uint16_t* __restrict__ lo, int n4) {
  int i = blockIdx.x * 256 + threadIdx.x;
  const int stride = gridDim.x * 256;
  for (; i < n4; i += stride) {
    float4 v = reinterpret_cast<const float4*>(src)[i];
    ushort4 h4, l4; uint16_t h, l;
    split2(v.x, h, l); h4.x = h; l4.x = l;
    split2(v.y, h, l); h4.y = h; l4.y = l;
    split2(v.z, h, l); h4.z = h; l4.z = l;
    split2(v.w, h, l); h4.w = h; l4.w = l;
    reinterpret_cast<ushort4*>(hi)[i] = h4;
    reinterpret_cast<ushort4*>(lo)[i] = l4;
  }
}

// ---------- kernel 1b: compress drop_mask (f32 {0,1.25}) -> 1 bit, causal words only ----------
__global__ __launch_bounds__(256) void k_mask_bits(const float* __restrict__ m,
                                                   unsigned long long* __restrict__ bits,
                                                   int n) {
  int i = blockIdx.x * 256 + threadIdx.x;
  const int stride = gridDim.x * 256;
  for (; i < n; i += stride) {
    const int srow = (i >> 11) & (S_ - 1);   // row within batch (S=2048)
    const int col  = i & (S_ - 1);
    if ((col & ~63) <= srow) {               // wave-uniform: skip strictly-above-diagonal words
      const unsigned long long b = __ballot(m[i] != 0.0f);
      if ((threadIdx.x & 63) == 0) bits[i >> 6] = b;
    }
  }
}

// ---------- kernel 2: transpose + split the three W's: Wt[p][d][k] = W[k][d] ----------
__global__ __launch_bounds__(256) void k_split_wt(const float* __restrict__ w0,
                                                  const float* __restrict__ w1,
                                                  const float* __restrict__ w2,
                                                  uint16_t* __restrict__ thi,
                                                  uint16_t* __restrict__ tlo) {
  const int pj = blockIdx.y;
  const float* w = pj == 0 ? w0 : (pj == 1 ? w1 : w2);
  const int idx = blockIdx.x * 256 + threadIdx.x;   // over DH*DIN, write-coalesced
  const int d = idx / DIN, k = idx % DIN;
  float f = w[k * DH + d];
  uint16_t h, l;
  split2(f, h, l);
  thi[(size_t)pj * DH * DIN + idx] = h;
  tlo[(size_t)pj * DH * DIN + idx] = l;
}

// ---------- kernel 3: fused QKV projection GEMM (split-bf16, 3-term) ----------
// Unified C^T geometry for all projections: A = W (M=d=128), B = x (N=s=64).
// Grid (M_/64, 3) = 768 blocks = exactly 3 blocks/CU (was 384 = 1.5/CU, imbalanced).
// Q/K epilogue: row-major [s][d] hi/lo (ushort4). V epilogue: V^T [d][s] 2B stores.
__global__ __launch_bounds__(256) void k_proj(
    const uint16_t* __restrict__ xhi, const uint16_t* __restrict__ xlo,
    const uint16_t* __restrict__ wthi, const uint16_t* __restrict__ wtlo,
    const float* __restrict__ bq, const float* __restrict__ bk, const float* __restrict__ bv,
    uint16_t* __restrict__ qhi, uint16_t* __restrict__ qlo,
    uint16_t* __restrict__ khi, uint16_t* __restrict__ klo,
    uint16_t* __restrict__ vt) {
  const int sblk = blockIdx.x;                     // 0..255, 64 s-rows each
  const int proj = blockIdx.y;
  const uint16_t* Whi = wthi + (size_t)proj * (DH * DIN);
  const uint16_t* Wlo = wtlo + (size_t)proj * (DH * DIN);

  const int tid = threadIdx.x;
  const int wid = tid >> 6, lane = tid & 63;
  const int g = lane >> 4, c16 = lane & 15;
  const int wr = wid >> 1, wc = wid & 1;           // wr: d-half (64), wc: s-half (32)

  uint32_t offA[4], offB[2];
#pragma unroll
  for (int i = 0; i < 4; ++i)
    offA[i] = (uint32_t)(wr * 64 + i * 16 + c16) * DIN + g * 8;
#pragma unroll
  for (int j = 0; j < 2; ++j)
    offB[j] = (uint32_t)(sblk * 64 + wc * 32 + j * 16 + c16) * DIN + g * 8;

  f32x4 acc[4][2] = {};
  bf16x8 aH0[4], aL0[4], bH0[2], bL0[2];
  bf16x8 aH1[4], aL1[4], bH1[2], bL1[2];

  auto LOAD = [&](bf16x8* AH, bf16x8* AL, bf16x8* BH, bf16x8* BL, int k) {
#pragma unroll
    for (int i = 0; i < 4; ++i) {
      AH[i] = ld8(Whi + offA[i] + k);
      AL[i] = ld8(Wlo + offA[i] + k);
    }
#pragma unroll
    for (int j = 0; j < 2; ++j) {
      BH[j] = ld8(xhi + offB[j] + k);
      BL[j] = ld8(xlo + offB[j] + k);
    }
  };
  auto FMA = [&](const bf16x8* AH, const bf16x8* AL, const bf16x8* BH, const bf16x8* BL) {
#pragma unroll
    for (int mf = 0; mf < 4; ++mf)
#pragma unroll
      for (int nf = 0; nf < 2; ++nf) {
        acc[mf][nf] = mfma(AH[mf], BH[nf], acc[mf][nf]);   // hi*hi
        acc[mf][nf] = mfma(AH[mf], BL[nf], acc[mf][nf]);   // hi*lo
        acc[mf][nf] = mfma(AL[mf], BH[nf], acc[mf][nf]);   // lo*hi
      }
  };

  LOAD(aH0, aL0, bH0, bL0, 0);
  for (int k = 0; k < DIN; k += 64) {            // register double-buffer, 2 chunks/iter
    LOAD(aH1, aL1, bH1, bL1, k + 32);
    FMA(aH0, aL0, bH0, bL0);
    if (k + 64 < DIN) LOAD(aH0, aL0, bH0, bL0, k + 64);
    FMA(aH1, aL1, bH1, bL1);
  }

  if (proj < 2) {
    const float* bias = (proj == 0) ? bq : bk;
    uint16_t* ohi = (proj == 0) ? qhi : khi;
    uint16_t* olo = (proj == 0) ? qlo : klo;
#pragma unroll
    for (int mf = 0; mf < 4; ++mf) {
      const int d0 = wr * 64 + mf * 16 + g * 4;    // C^T row = d = 4g+r
      const float4 bs = *reinterpret_cast<const float4*>(bias + d0);
#pragma unroll
      for (int nf = 0; nf < 2; ++nf) {
        const int srow = sblk * 64 + wc * 32 + nf * 16 + c16;  // C^T col = s
        f32x4 v = acc[mf][nf];
        ushort4 h4, l4; uint16_t h, l;
        split2(v[0] + bs.x, h, l); h4.x = h; l4.x = l;
        split2(v[1] + bs.y, h, l); h4.y = h; l4.y = l;
        split2(v[2] + bs.z, h, l); h4.z = h; l4.z = l;
        split2(v[3] + bs.w, h, l); h4.w = h; l4.w = l;
        *reinterpret_cast<ushort4*>(ohi + (size_t)srow * DH + d0) = h4;
        *reinterpret_cast<ushort4*>(olo + (size_t)srow * DH + d0) = l4;
      }
    }
  } else {
    // V^T [b][d][s]: per lane 4 consecutive d-rows at fixed s -> 2B stores, lanes
    // contiguous in s (16 lanes x 2B = 32B runs). 4MB total, acceptable.
#pragma unroll
    for (int mf = 0; mf < 4; ++mf) {
      const int d0 = wr * 64 + mf * 16 + g * 4;
      const float4 bs = *reinterpret_cast<const float4*>(bv + d0);
#pragma unroll
      for (int nf = 0; nf < 2; ++nf) {
        const int srow = sblk * 64 + wc * 32 + nf * 16 + c16;
        const int b = srow >> 11;
        const int sin = srow & (S_ - 1);
        f32x4 v = acc[mf][nf];
        vt[((size_t)b * DH + d0 + 0) * S_ + sin] = bf16_rne(v[0] + bs.x);
        vt[((size_t)b * DH + d0 + 1) * S_ + sin] = bf16_rne(v[1] + bs.y);
        vt[((size_t)b * DH + d0 + 2) * S_ + sin] = bf16_rne(v[2] + bs.z);
        vt[((size_t)b * DH + d0 + 3) * S_ + sin] = bf16_rne(v[3] + bs.w);
      }
    }
  }
}

// ---------- kernel 4: causal attention, intra-block split-K flash ----------
// Block = 4 waves sharing ONE 16-row q-tile; wave w takes k-tiles t = w, w+4, ...
// (online softmax is associative -> per-wave partial (m,l,acc), LDS combine at end).
__global__ __launch_bounds__(256) void k_attn(
    const uint16_t* __restrict__ qhi, const uint16_t* __restrict__ qlo,
    const uint16_t* __restrict__ khi, const uint16_t* __restrict__ klo,
    const uint16_t* __restrict__ vt,
    const unsigned long long* __restrict__ bits,
    float* __restrict__ out) {
  __shared__ float accL[4][128][16];               // 32KB partial accumulators [w][d][q]
  __shared__ float smL[4][16], slL[4][16];         // partial m, l  [w][q]
  __shared__ uint16_t plds[4][16][72];             // per-wave P tile [q][k], +8 pad
  const int tid = threadIdx.x;
  const int wid = tid >> 6, lane = tid & 63;
  const int g = lane >> 4, c16 = lane & 15;
  const int b = blockIdx.x >> 7;
  const int qt = 127 - (blockIdx.x & 127);         // big q-tiles launch first (tail fill)
  const int q0 = qt * 16;
  const int qrow = q0 + c16;

  const uint32_t qoff = (uint32_t)(b * S_ + qrow) * DH + g * 8;
  bf16x8 qH[4], qL[4];
#pragma unroll
  for (int c2 = 0; c2 < 4; ++c2) {
    qH[c2] = ld8(qhi + qoff + c2 * 32);
    qL[c2] = ld8(qlo + qoff + c2 * 32);
  }

  f32x4 acc[8] = {};                               // out^T frags: d=128, q=16
  float m_run = -1e30f, l_run = 0.0f;
  const int ntile = (q0 + 16 + 63) >> 6;
  const uint32_t brow = (uint32_t)(b * S_ + qrow) * (S_ / 64);

  for (int t = wid; t < ntile; t += 4) {
    const int j0 = t * 64;
    const unsigned long long bw = bits[brow + t];  // dropout bits, use is far below
    // S^T = K * Q^T   (split: hi*hi + hi*lo + lo*hi)
    f32x4 st[4] = {};
#pragma unroll
    for (int kf = 0; kf < 4; ++kf) {
      const uint32_t koff = (uint32_t)(b * S_ + j0 + kf * 16 + c16) * DH + g * 8;
#pragma unroll
      for (int c2 = 0; c2 < 4; ++c2) {
        const bf16x8 kH = ld8(khi + koff + c2 * 32);
        const bf16x8 kL = ld8(klo + koff + c2 * 32);
        st[kf] = mfma(kH, qH[c2], st[kf]);
        st[kf] = mfma(kH, qL[c2], st[kf]);
        st[kf] = mfma(kL, qH[c2], st[kf]);
      }
    }
    // causal + (wei==0 -> -inf) + row max (lane holds 16 k's of its q-row)
    float tmax = -INFINITY;
#pragma unroll
    for (int kf = 0; kf < 4; ++kf)
#pragma unroll
      for (int r = 0; r < 4; ++r) {
        const int kg = j0 + kf * 16 + g * 4 + r;   // C row = k
        float s = st[kf][r];
        s = (kg <= qrow && s != 0.0f) ? s : -INFINITY;
        st[kf][r] = s;
        tmax = fmaxf(tmax, s);
      }
    tmax = fmaxf(tmax, __shfl_xor(tmax, 16));
    tmax = fmaxf(tmax, __shfl_xor(tmax, 32));
    const float m_new = fmaxf(m_run, tmax);
    const float fs = __expf(m_run - m_new);
    m_run = m_new;
    float psum = 0.0f;
#pragma unroll
    for (int kf = 0; kf < 4; ++kf)
#pragma unroll
      for (int r = 0; r < 4; ++r) {
        const float pv = __expf(st[kf][r] - m_new);
        psum += pv;
        st[kf][r] = pv;
      }
    l_run = l_run * fs + psum;                     // denominator: no dropout
    // dropout via bits (bit -> *1.25 exactly matches the f32 mask), P -> bf16 -> LDS [q][k]
#pragma unroll
    for (int kf = 0; kf < 4; ++kf) {
      const int bi = kf * 16 + g * 4;
      ushort4 pb;
      pb.x = bf16_rne(((bw >> (bi + 0)) & 1ull) ? st[kf][0] * 1.25f : 0.0f);
      pb.y = bf16_rne(((bw >> (bi + 1)) & 1ull) ? st[kf][1] * 1.25f : 0.0f);
      pb.z = bf16_rne(((bw >> (bi + 2)) & 1ull) ? st[kf][2] * 1.25f : 0.0f);
      pb.w = bf16_rne(((bw >> (bi + 3)) & 1ull) ? st[kf][3] * 1.25f : 0.0f);
      *reinterpret_cast<ushort4*>(&plds[wid][c16][kf * 16 + g * 4]) = pb;
    }
#pragma unroll
    for (int mf = 0; mf < 8; ++mf) acc[mf] *= fs;  // rescale accumulator
    // PV: out^T += V^T * P^T
#pragma unroll
    for (int kc = 0; kc < 2; ++kc) {
      const bf16x8 pB = *reinterpret_cast<const bf16x8*>(&plds[wid][c16][kc * 32 + g * 8]);
#pragma unroll
      for (int mf = 0; mf < 8; ++mf) {
        const uint32_t voff = (uint32_t)(b * DH + mf * 16 + c16) * S_ + j0 + kc * 32 + g * 8;
        acc[mf] = mfma(ld8(vt + voff), pB, acc[mf]);
      }
    }
  }
  // ---- intra-wave finish, publish partials ----
  l_run += __shfl_xor(l_run, 16);
  l_run += __shfl_xor(l_run, 32);
  if (lane < 16) { smL[wid][lane] = m_run; slL[wid][lane] = l_run; }
#pragma unroll
  for (int mf = 0; mf < 8; ++mf) {
    const int d = mf * 16 + g * 4;
#pragma unroll
    for (int r = 0; r < 4; ++r) accL[wid][d + r][c16] = acc[mf][r];
  }
  __syncthreads();
  // ---- block combine: wave wid merges d-rows [32*wid, 32*wid+32) ----
  const float m0 = smL[0][c16], m1 = smL[1][c16], m2 = smL[2][c16], m3 = smL[3][c16];
  const float mm = fmaxf(fmaxf(m0, m1), fmaxf(m2, m3));
  const float f0 = __expf(m0 - mm), f1 = __expf(m1 - mm);
  const float f2 = __expf(m2 - mm), f3 = __expf(m3 - mm);
  const float ll = slL[0][c16] * f0 + slL[1][c16] * f1 + slL[2][c16] * f2 + slL[3][c16] * f3;
  const float inv = 1.0f / ll;
  const uint32_t orow = (uint32_t)(b * S_ + qrow) * DH;
#pragma unroll
  for (int i = 0; i < 2; ++i) {
    const int d = (wid * 2 + i) * 16 + g * 4;
    float4 o;
    o.x = (accL[0][d + 0][c16] * f0 + accL[1][d + 0][c16] * f1 +
           accL[2][d + 0][c16] * f2 + accL[3][d + 0][c16] * f3) * inv;
    o.y = (accL[0][d + 1][c16] * f0 + accL[1][d + 1][c16] * f1 +
           accL[2][d + 1][c16] * f2 + accL[3][d + 1][c16] * f3) * inv;
    o.z = (accL[0][d + 2][c16] * f0 + accL[1][d + 2][c16] * f1 +
           accL[2][d + 2][c16] * f2 + accL[3][d + 2][c16] * f3) * inv;
    o.w = (accL[0][d + 3][c16] * f0 + accL[1][d + 3][c16] * f1 +
           accL[2][d + 3][c16] * f2 + accL[3][d + 3][c16] * f3) * inv;
    *reinterpret_cast<float4*>(out + orow + d) = o;
  }
}

extern "C" void kernel_launch(void* const* d_in, const int* in_sizes, int n_in,
                              void* d_out, int out_size, void* d_ws, size_t ws_size,
                              hipStream_t stream) {
  const float* x    = (const float*)d_in[0];
  const float* Wq   = (const float*)d_in[1];
  const float* bq   = (const float*)d_in[2];
  const float* Wk   = (const float*)d_in[3];
  const float* bk   = (const float*)d_in[4];
  const float* Wv   = (const float*)d_in[5];
  const float* bv   = (const float*)d_in[6];
  const float* mask = (const float*)d_in[7];
  float* out = (float*)d_out;

  char* p = (char*)d_ws;
  auto take = [&](size_t bytes) {
    char* r = p;
    p += (bytes + 255) & ~(size_t)255;
    return r;
  };
  uint16_t* xhi  = (uint16_t*)take((size_t)M_ * DIN * 2);
  uint16_t* xlo  = (uint16_t*)take((size_t)M_ * DIN * 2);
  uint16_t* wthi = (uint16_t*)take((size_t)3 * DH * DIN * 2);
  uint16_t* wtlo = (uint16_t*)take((size_t)3 * DH * DIN * 2);
  uint16_t* qhi  = (uint16_t*)take((size_t)M_ * DH * 2);
  uint16_t* qlo  = (uint16_t*)take((size_t)M_ * DH * 2);
  uint16_t* khi  = (uint16_t*)take((size_t)M_ * DH * 2);
  uint16_t* klo  = (uint16_t*)take((size_t)M_ * DH * 2);
  uint16_t* vt   = (uint16_t*)take((size_t)M_ * DH * 2);
  unsigned long long* bits = (unsigned long long*)take((size_t)B_ * S_ * S_ / 8);

  k_split_x<<<2048, 256, 0, stream>>>(x, xhi, xlo, M_ * DIN / 4);
  k_mask_bits<<<2048, 256, 0, stream>>>(mask, bits, B_ * S_ * S_);
  k_split_wt<<<dim3(DH * DIN / 256, 3), 256, 0, stream>>>(Wq, Wk, Wv, wthi, wtlo);
  k_proj<<<dim3(M_ / 64, 3), 256, 0, stream>>>(xhi, xlo, wthi, wtlo, bq, bk, bv,
                                               qhi, qlo, khi, klo, vt);
  k_attn<<<B_ * S_ / 16, 256, 0, stream>>>(qhi, qlo, khi, klo, vt, bits, out);
}

// Round 8
// 442.641 us; speedup vs baseline: 1.2835x; 1.2835x over previous
//
#include <hip/hip_runtime.h>
#include <cstdint>
#include <cmath>

#define DEV static __device__ __forceinline__

typedef __attribute__((ext_vector_type(8))) short bf16x8;   // 8 bf16 in 4 VGPRs
typedef __attribute__((ext_vector_type(4))) float f32x4;    // MFMA accumulator

constexpr int B_  = 8;
constexpr int S_  = 2048;
constexpr int DIN = 1024;
constexpr int DH  = 128;
constexpr int M_  = B_ * S_;   // 16384 token rows

// ---------- bf16 helpers (manual, RNE) ----------
DEV uint16_t bf16_rne(float f) {
  uint32_t u = __float_as_uint(f);
  u += 0x7FFFu + ((u >> 16) & 1u);
  return (uint16_t)(u >> 16);
}
DEV float bf16_f32(uint16_t h) { return __uint_as_float(((uint32_t)h) << 16); }
DEV void split2(float f, uint16_t& h, uint16_t& l) {
  h = bf16_rne(f);
  l = bf16_rne(f - bf16_f32(h));   // exact residual, then round: ~2^-17 combined
}
DEV f32x4 mfma(bf16x8 a, bf16x8 b, f32x4 c) {
  return __builtin_amdgcn_mfma_f32_16x16x32_bf16(a, b, c, 0, 0, 0);
}
DEV bf16x8 ld8(const uint16_t* p) { return *reinterpret_cast<const bf16x8*>(p); }
// async global->LDS, 16B per lane; LDS dest must be lane-linear (wave base + lane*16)
DEV void gload_lds16(const uint16_t* g, uint16_t* l) {
  __builtin_amdgcn_global_load_lds(
      (const __attribute__((address_space(1))) void*)g,
      (__attribute__((address_space(3))) void*)l, 16, 0, 0);
}

// ---------- kernel 1: split x (f32 -> hi/lo bf16) ----------
__global__ __launch_bounds__(256) void k_split_x(const float* __restrict__ src,
                                                 uint16_t* __restrict__ hi,
                                                 uint16_t* __restrict__ lo, int n4) {
  int i = blockIdx.x * 256 + threadIdx.x;
  const int stride = gridDim.x * 256;
  for (; i < n4; i += stride) {
    float4 v = reinterpret_cast<const float4*>(src)[i];
    ushort4 h4, l4; uint16_t h, l;
    split2(v.x, h, l); h4.x = h; l4.x = l;
    split2(v.y, h, l); h4.y = h; l4.y = l;
    split2(v.z, h, l); h4.z = h; l4.z = l;
    split2(v.w, h, l); h4.w = h; l4.w = l;
    reinterpret_cast<ushort4*>(hi)[i] = h4;
    reinterpret_cast<ushort4*>(lo)[i] = l4;
  }
}

// ---------- kernel 1b: compress drop_mask (f32 {0,1.25}) -> 1 bit, causal words only ----------
__global__ __launch_bounds__(256) void k_mask_bits(const float* __restrict__ m,
                                                   unsigned long long* __restrict__ bits,
                                                   int n) {
  int i = blockIdx.x * 256 + threadIdx.x;
  const int stride = gridDim.x * 256;
  for (; i < n; i += stride) {
    const int srow = (i >> 11) & (S_ - 1);   // row within batch (S=2048)
    const int col  = i & (S_ - 1);
    if ((col & ~63) <= srow) {               // wave-uniform: skip strictly-above-diagonal words
      const unsigned long long b = __ballot(m[i] != 0.0f);
      if ((threadIdx.x & 63) == 0) bits[i >> 6] = b;
    }
  }
}

// ---------- kernel 2: transpose + split the three W's: Wt[p][d][k] = W[k][d] ----------
__global__ __launch_bounds__(256) void k_split_wt(const float* __restrict__ w0,
                                                  const float* __restrict__ w1,
                                                  const float* __restrict__ w2,
                                                  uint16_t* __restrict__ thi,
                                                  uint16_t* __restrict__ tlo) {
  const int pj = blockIdx.y;
  const float* w = pj == 0 ? w0 : (pj == 1 ? w1 : w2);
  const int idx = blockIdx.x * 256 + threadIdx.x;   // over DH*DIN, write-coalesced
  const int d = idx / DIN, k = idx % DIN;
  float f = w[k * DH + d];
  uint16_t h, l;
  split2(f, h, l);
  thi[(size_t)pj * DH * DIN + idx] = h;
  tlo[(size_t)pj * DH * DIN + idx] = l;
}

// ---------- kernel 3: fused QKV projection GEMM, LDS-staged (m97 recipe) ----------
// Tile: 128d x 64s, BK=64, 4 waves (wr: d-half, wc: s-half). W/x hi+lo staged into
// 48KB LDS via global_load_lds (lane-linear dest, XOR-swizzled GLOBAL source);
// ds_read_b128 fragments with matching XOR -> 2-way (free) bank aliasing.
__global__ __launch_bounds__(256) void k_proj(
    const uint16_t* __restrict__ xhi, const uint16_t* __restrict__ xlo,
    const uint16_t* __restrict__ wthi, const uint16_t* __restrict__ wtlo,
    const float* __restrict__ bq, const float* __restrict__ bk, const float* __restrict__ bv,
    uint16_t* __restrict__ qhi, uint16_t* __restrict__ qlo,
    uint16_t* __restrict__ khi, uint16_t* __restrict__ klo,
    uint16_t* __restrict__ vt) {
  __shared__ uint16_t As_hi[128][64], As_lo[128][64];   // W tile  [d][k]  16+16 KB
  __shared__ uint16_t Bs_hi[64][64],  Bs_lo[64][64];    // x tile  [s][k]   8+8 KB
  const int sblk = blockIdx.x;                     // 0..255, 64 s-rows each
  const int proj = blockIdx.y;
  const uint16_t* Whi = wthi + (size_t)proj * (DH * DIN);
  const uint16_t* Wlo = wtlo + (size_t)proj * (DH * DIN);

  const int tid = threadIdx.x;
  const int wid = tid >> 6, lane = tid & 63;
  const int g = lane >> 4, c16 = lane & 15;
  const int wr = wid >> 1, wc = wid & 1;           // wr: d-half (64), wc: s-half (32)

  f32x4 acc[4][2] = {};

  // stage one BK=64 chunk: A hi/lo 1024 16B-chunks each (4/thread), B hi/lo 512 (2/thread)
  auto STAGE = [&](int k0) {
#pragma unroll
    for (int i = 0; i < 4; ++i) {
      const int c = tid + i * 256;
      const int row = c >> 3, sl = c & 7;          // 8 slots of 16B per 64-elem row
      const int col = (sl ^ (row & 7)) * 8;        // pre-swizzle global source
      const uint32_t so = (uint32_t)row * DIN + k0 + col;
      gload_lds16(Whi + so, &As_hi[0][0] + c * 8);
      gload_lds16(Wlo + so, &As_lo[0][0] + c * 8);
    }
#pragma unroll
    for (int i = 0; i < 2; ++i) {
      const int c = tid + i * 256;
      const int row = c >> 3, sl = c & 7;
      const int col = (sl ^ (row & 7)) * 8;
      const uint32_t so = (uint32_t)(sblk * 64 + row) * DIN + k0 + col;
      gload_lds16(xhi + so, &Bs_hi[0][0] + c * 8);
      gload_lds16(xlo + so, &Bs_lo[0][0] + c * 8);
    }
  };
  auto COMPUTE = [&]() {
#pragma unroll
    for (int kk = 0; kk < 2; ++kk) {               // two 32-K halves of the chunk
      bf16x8 AH[4], AL[4], BH[2], BL[2];
#pragma unroll
      for (int mf = 0; mf < 4; ++mf) {
        const int row = wr * 64 + mf * 16 + c16;
        const int col = ((g + kk * 4) ^ (row & 7)) * 8;   // un-swizzle on read
        AH[mf] = ld8(&As_hi[row][col]);
        AL[mf] = ld8(&As_lo[row][col]);
      }
#pragma unroll
      for (int nf = 0; nf < 2; ++nf) {
        const int row = wc * 32 + nf * 16 + c16;
        const int col = ((g + kk * 4) ^ (row & 7)) * 8;
        BH[nf] = ld8(&Bs_hi[row][col]);
        BL[nf] = ld8(&Bs_lo[row][col]);
      }
#pragma unroll
      for (int mf = 0; mf < 4; ++mf)
#pragma unroll
        for (int nf = 0; nf < 2; ++nf) {
          acc[mf][nf] = mfma(AH[mf], BH[nf], acc[mf][nf]);   // hi*hi
          acc[mf][nf] = mfma(AH[mf], BL[nf], acc[mf][nf]);   // hi*lo
          acc[mf][nf] = mfma(AL[mf], BH[nf], acc[mf][nf]);   // lo*hi
        }
    }
  };

  for (int k0 = 0; k0 < DIN; k0 += 64) {           // m97 2-barrier loop
    __syncthreads();                               // prior compute done before overwrite
    STAGE(k0);
    __syncthreads();                               // compiler drains vmcnt before barrier
    COMPUTE();
  }

  if (proj < 2) {
    const float* bias = (proj == 0) ? bq : bk;
    uint16_t* ohi = (proj == 0) ? qhi : khi;
    uint16_t* olo = (proj == 0) ? qlo : klo;
#pragma unroll
    for (int mf = 0; mf < 4; ++mf) {
      const int d0 = wr * 64 + mf * 16 + g * 4;    // C^T row = d = 4g+r
      const float4 bs = *reinterpret_cast<const float4*>(bias + d0);
#pragma unroll
      for (int nf = 0; nf < 2; ++nf) {
        const int srow = sblk * 64 + wc * 32 + nf * 16 + c16;  // C^T col = s
        f32x4 v = acc[mf][nf];
        ushort4 h4, l4; uint16_t h, l;
        split2(v[0] + bs.x, h, l); h4.x = h; l4.x = l;
        split2(v[1] + bs.y, h, l); h4.y = h; l4.y = l;
        split2(v[2] + bs.z, h, l); h4.z = h; l4.z = l;
        split2(v[3] + bs.w, h, l); h4.w = h; l4.w = l;
        *reinterpret_cast<ushort4*>(ohi + (size_t)srow * DH + d0) = h4;
        *reinterpret_cast<ushort4*>(olo + (size_t)srow * DH + d0) = l4;
      }
    }
  } else {
    // V^T [b][d][s]: per lane 4 consecutive d-rows at fixed s -> 2B stores (32B runs).
#pragma unroll
    for (int mf = 0; mf < 4; ++mf) {
      const int d0 = wr * 64 + mf * 16 + g * 4;
      const float4 bs = *reinterpret_cast<const float4*>(bv + d0);
#pragma unroll
      for (int nf = 0; nf < 2; ++nf) {
        const int srow = sblk * 64 + wc * 32 + nf * 16 + c16;
        const int b = srow >> 11;
        const int sin = srow & (S_ - 1);
        f32x4 v = acc[mf][nf];
        vt[((size_t)b * DH + d0 + 0) * S_ + sin] = bf16_rne(v[0] + bs.x);
        vt[((size_t)b * DH + d0 + 1) * S_ + sin] = bf16_rne(v[1] + bs.y);
        vt[((size_t)b * DH + d0 + 2) * S_ + sin] = bf16_rne(v[2] + bs.z);
        vt[((size_t)b * DH + d0 + 3) * S_ + sin] = bf16_rne(v[3] + bs.w);
      }
    }
  }
}

// ---------- kernel 4: causal attention (round-2 form: 1 wave = 1 q-tile) ----------
// Swapped QK^T (mfma(K,Q)) so lane owns one q-row's scores. Reverse-paired q-tiles.
__global__ __launch_bounds__(256) void k_attn(
    const uint16_t* __restrict__ qhi, const uint16_t* __restrict__ qlo,
    const uint16_t* __restrict__ khi, const uint16_t* __restrict__ klo,
    const uint16_t* __restrict__ vt,
    const unsigned long long* __restrict__ bits,
    float* __restrict__ out) {
  __shared__ uint16_t plds[4][16][72];             // per-wave P tile [q][k], +8 pad
  const int tid = threadIdx.x;
  const int wid = tid >> 6, lane = tid & 63;
  const int g = lane >> 4, c16 = lane & 15;
  const int unit = blockIdx.x * 4 + wid;
  const int b = unit >> 7;
  const int uu = unit & 127;
  // reverse-pair q-tiles so every block gets ~equal causal work
  const int qt = (uu & 1) ? (127 - (uu >> 1)) : (uu >> 1);
  const int q0 = qt * 16;
  const int qrow = q0 + c16;

  const uint32_t qoff = (uint32_t)(b * S_ + qrow) * DH + g * 8;
  bf16x8 qH[4], qL[4];
#pragma unroll
  for (int c2 = 0; c2 < 4; ++c2) {
    qH[c2] = ld8(qhi + qoff + c2 * 32);
    qL[c2] = ld8(qlo + qoff + c2 * 32);
  }

  f32x4 acc[8] = {};                               // out^T frags: d=128, q=16
  float m_run = -1e30f, l_run = 0.0f;
  const int ntile = (q0 + 16 + 63) >> 6;
  const uint32_t brow = (uint32_t)(b * S_ + qrow) * (S_ / 64);

  for (int t = 0; t < ntile; ++t) {
    const int j0 = t * 64;
    const unsigned long long bw = bits[brow + t];  // dropout bits, use is far below
    // S^T = K * Q^T   (split: hi*hi + hi*lo + lo*hi)
    f32x4 st[4] = {};
#pragma unroll
    for (int kf = 0; kf < 4; ++kf) {
      const uint32_t koff = (uint32_t)(b * S_ + j0 + kf * 16 + c16) * DH + g * 8;
#pragma unroll
      for (int c2 = 0; c2 < 4; ++c2) {
        const bf16x8 kH = ld8(khi + koff + c2 * 32);
        const bf16x8 kL = ld8(klo + koff + c2 * 32);
        st[kf] = mfma(kH, qH[c2], st[kf]);
        st[kf] = mfma(kH, qL[c2], st[kf]);
        st[kf] = mfma(kL, qH[c2], st[kf]);
      }
    }
    // causal + (wei==0 -> -inf) + row max (lane holds 16 k's of its q-row)
    float tmax = -INFINITY;
#pragma unroll
    for (int kf = 0; kf < 4; ++kf)
#pragma unroll
      for (int r = 0; r < 4; ++r) {
        const int kg = j0 + kf * 16 + g * 4 + r;   // C row = k
        float s = st[kf][r];
        s = (kg <= qrow && s != 0.0f) ? s : -INFINITY;
        st[kf][r] = s;
        tmax = fmaxf(tmax, s);
      }
    tmax = fmaxf(tmax, __shfl_xor(tmax, 16));
    tmax = fmaxf(tmax, __shfl_xor(tmax, 32));
    const float m_new = fmaxf(m_run, tmax);
    const float fs = __expf(m_run - m_new);
    m_run = m_new;
    float psum = 0.0f;
#pragma unroll
    for (int kf = 0; kf < 4; ++kf)
#pragma unroll
      for (int r = 0; r < 4; ++r) {
        const float pv = __expf(st[kf][r] - m_new);
        psum += pv;
        st[kf][r] = pv;
      }
    l_run = l_run * fs + psum;                     // denominator: no dropout
    // dropout via bits (bit -> *1.25 exactly matches the f32 mask), P -> bf16 -> LDS [q][k]
#pragma unroll
    for (int kf = 0; kf < 4; ++kf) {
      const int bi = kf * 16 + g * 4;
      ushort4 pb;
      pb.x = bf16_rne(((bw >> (bi + 0)) & 1ull) ? st[kf][0] * 1.25f : 0.0f);
      pb.y = bf16_rne(((bw >> (bi + 1)) & 1ull) ? st[kf][1] * 1.25f : 0.0f);
      pb.z = bf16_rne(((bw >> (bi + 2)) & 1ull) ? st[kf][2] * 1.25f : 0.0f);
      pb.w = bf16_rne(((bw >> (bi + 3)) & 1ull) ? st[kf][3] * 1.25f : 0.0f);
      *reinterpret_cast<ushort4*>(&plds[wid][c16][kf * 16 + g * 4]) = pb;
    }
#pragma unroll
    for (int mf = 0; mf < 8; ++mf) acc[mf] *= fs;  // rescale accumulator
    // PV: out^T += V^T * P^T
#pragma unroll
    for (int kc = 0; kc < 2; ++kc) {
      const bf16x8 pB = *reinterpret_cast<const bf16x8*>(&plds[wid][c16][kc * 32 + g * 8]);
#pragma unroll
      for (int mf = 0; mf < 8; ++mf) {
        const uint32_t voff = (uint32_t)(b * DH + mf * 16 + c16) * S_ + j0 + kc * 32 + g * 8;
        acc[mf] = mfma(ld8(vt + voff), pB, acc[mf]);
      }
    }
  }
  l_run += __shfl_xor(l_run, 16);
  l_run += __shfl_xor(l_run, 32);
  const float inv = 1.0f / l_run;
  const uint32_t orow = (uint32_t)(b * S_ + qrow) * DH;
#pragma unroll
  for (int mf = 0; mf < 8; ++mf) {
    float4 o;
    o.x = acc[mf][0] * inv;
    o.y = acc[mf][1] * inv;
    o.z = acc[mf][2] * inv;
    o.w = acc[mf][3] * inv;
    *reinterpret_cast<float4*>(out + orow + mf * 16 + g * 4) = o;   // row=d, col=q
  }
}

extern "C" void kernel_launch(void* const* d_in, const int* in_sizes, int n_in,
                              void* d_out, int out_size, void* d_ws, size_t ws_size,
                              hipStream_t stream) {
  const float* x    = (const float*)d_in[0];
  const float* Wq   = (const float*)d_in[1];
  const float* bq   = (const float*)d_in[2];
  const float* Wk   = (const float*)d_in[3];
  const float* bk   = (const float*)d_in[4];
  const float* Wv   = (const float*)d_in[5];
  const float* bv   = (const float*)d_in[6];
  const float* mask = (const float*)d_in[7];
  float* out = (float*)d_out;

  char* p = (char*)d_ws;
  auto take = [&](size_t bytes) {
    char* r = p;
    p += (bytes + 255) & ~(size_t)255;
    return r;
  };
  uint16_t* xhi  = (uint16_t*)take((size_t)M_ * DIN * 2);
  uint16_t* xlo  = (uint16_t*)take((size_t)M_ * DIN * 2);
  uint16_t* wthi = (uint16_t*)take((size_t)3 * DH * DIN * 2);
  uint16_t* wtlo = (uint16_t*)take((size_t)3 * DH * DIN * 2);
  uint16_t* qhi  = (uint16_t*)take((size_t)M_ * DH * 2);
  uint16_t* qlo  = (uint16_t*)take((size_t)M_ * DH * 2);
  uint16_t* khi  = (uint16_t*)take((size_t)M_ * DH * 2);
  uint16_t* klo  = (uint16_t*)take((size_t)M_ * DH * 2);
  uint16_t* vt   = (uint16_t*)take((size_t)M_ * DH * 2);
  unsigned long long* bits = (unsigned long long*)take((size_t)B_ * S_ * S_ / 8);

  k_split_x<<<2048, 256, 0, stream>>>(x, xhi, xlo, M_ * DIN / 4);
  k_mask_bits<<<2048, 256, 0, stream>>>(mask, bits, B_ * S_ * S_);
  k_split_wt<<<dim3(DH * DIN / 256, 3), 256, 0, stream>>>(Wq, Wk, Wv, wthi, wtlo);
  k_proj<<<dim3(M_ / 64, 3), 256, 0, stream>>>(xhi, xlo, wthi, wtlo, bq, bk, bv,
                                               qhi, qlo, khi, klo, vt);
  k_attn<<<(B_ * S_ / 16) / 4, 256, 0, stream>>>(qhi, qlo, khi, klo, vt, bits, out);
}

// Round 9
// 392.394 us; speedup vs baseline: 1.4478x; 1.1281x over previous
//
#include <hip/hip_runtime.h>
#include <cstdint>
#include <cmath>

#define DEV static __device__ __forceinline__

typedef __attribute__((ext_vector_type(8))) short bf16x8;   // 8 bf16 in 4 VGPRs
typedef __attribute__((ext_vector_type(4))) float f32x4;    // MFMA accumulator

constexpr int B_  = 8;
constexpr int S_  = 2048;
constexpr int DIN = 1024;
constexpr int DH  = 128;
constexpr int M_  = B_ * S_;   // 16384 token rows

// ---------- bf16 helpers (manual, RNE) ----------
DEV uint16_t bf16_rne(float f) {
  uint32_t u = __float_as_uint(f);
  u += 0x7FFFu + ((u >> 16) & 1u);
  return (uint16_t)(u >> 16);
}
DEV float bf16_f32(uint16_t h) { return __uint_as_float(((uint32_t)h) << 16); }
DEV void split2(float f, uint16_t& h, uint16_t& l) {
  h = bf16_rne(f);
  l = bf16_rne(f - bf16_f32(h));   // exact residual, then round: ~2^-17 combined
}
DEV f32x4 mfma(bf16x8 a, bf16x8 b, f32x4 c) {
  return __builtin_amdgcn_mfma_f32_16x16x32_bf16(a, b, c, 0, 0, 0);
}
DEV bf16x8 ld8(const uint16_t* p) { return *reinterpret_cast<const bf16x8*>(p); }
// async global->LDS, 16B per lane; LDS dest must be lane-linear (wave base + lane*16)
DEV void gload_lds16(const uint16_t* g, uint16_t* l) {
  __builtin_amdgcn_global_load_lds(
      (const __attribute__((address_space(1))) void*)g,
      (__attribute__((address_space(3))) void*)l, 16, 0, 0);
}

// ---------- kernel 1: split x (f32 -> hi/lo bf16) ----------
__global__ __launch_bounds__(256) void k_split_x(const float* __restrict__ src,
                                                 uint16_t* __restrict__ hi,
                                                 uint16_t* __restrict__ lo, int n4) {
  int i = blockIdx.x * 256 + threadIdx.x;
  const int stride = gridDim.x * 256;
  for (; i < n4; i += stride) {
    float4 v = reinterpret_cast<const float4*>(src)[i];
    ushort4 h4, l4; uint16_t h, l;
    split2(v.x, h, l); h4.x = h; l4.x = l;
    split2(v.y, h, l); h4.y = h; l4.y = l;
    split2(v.z, h, l); h4.z = h; l4.z = l;
    split2(v.w, h, l); h4.w = h; l4.w = l;
    reinterpret_cast<ushort4*>(hi)[i] = h4;
    reinterpret_cast<ushort4*>(lo)[i] = l4;
  }
}

// ---------- kernel 1b: compress drop_mask (f32 {0,1.25}) -> 1 bit, causal words only ----------
__global__ __launch_bounds__(256) void k_mask_bits(const float* __restrict__ m,
                                                   unsigned long long* __restrict__ bits,
                                                   int n) {
  int i = blockIdx.x * 256 + threadIdx.x;
  const int stride = gridDim.x * 256;
  for (; i < n; i += stride) {
    const int srow = (i >> 11) & (S_ - 1);   // row within batch (S=2048)
    const int col  = i & (S_ - 1);
    if ((col & ~63) <= srow) {               // wave-uniform: skip strictly-above-diagonal words
      const unsigned long long b = __ballot(m[i] != 0.0f);
      if ((threadIdx.x & 63) == 0) bits[i >> 6] = b;
    }
  }
}

// ---------- kernel 2: transpose + split the three W's: Wt[p][d][k] = W[k][d] ----------
__global__ __launch_bounds__(256) void k_split_wt(const float* __restrict__ w0,
                                                  const float* __restrict__ w1,
                                                  const float* __restrict__ w2,
                                                  uint16_t* __restrict__ thi,
                                                  uint16_t* __restrict__ tlo) {
  const int pj = blockIdx.y;
  const float* w = pj == 0 ? w0 : (pj == 1 ? w1 : w2);
  const int idx = blockIdx.x * 256 + threadIdx.x;   // over DH*DIN, write-coalesced
  const int d = idx / DIN, k = idx % DIN;
  float f = w[k * DH + d];
  uint16_t h, l;
  split2(f, h, l);
  thi[(size_t)pj * DH * DIN + idx] = h;
  tlo[(size_t)pj * DH * DIN + idx] = l;
}

// ---------- kernel 3: fused QKV projection GEMM, LDS-staged (m97 recipe) ----------
__global__ __launch_bounds__(256) void k_proj(
    const uint16_t* __restrict__ xhi, const uint16_t* __restrict__ xlo,
    const uint16_t* __restrict__ wthi, const uint16_t* __restrict__ wtlo,
    const float* __restrict__ bq, const float* __restrict__ bk, const float* __restrict__ bv,
    uint16_t* __restrict__ qhi, uint16_t* __restrict__ qlo,
    uint16_t* __restrict__ khi, uint16_t* __restrict__ klo,
    uint16_t* __restrict__ vt) {
  __shared__ uint16_t As_hi[128][64], As_lo[128][64];   // W tile  [d][k]  16+16 KB
  __shared__ uint16_t Bs_hi[64][64],  Bs_lo[64][64];    // x tile  [s][k]   8+8 KB
  const int sblk = blockIdx.x;                     // 0..255, 64 s-rows each
  const int proj = blockIdx.y;
  const uint16_t* Whi = wthi + (size_t)proj * (DH * DIN);
  const uint16_t* Wlo = wtlo + (size_t)proj * (DH * DIN);

  const int tid = threadIdx.x;
  const int wid = tid >> 6, lane = tid & 63;
  const int g = lane >> 4, c16 = lane & 15;
  const int wr = wid >> 1, wc = wid & 1;           // wr: d-half (64), wc: s-half (32)

  f32x4 acc[4][2] = {};

  auto STAGE = [&](int k0) {
#pragma unroll
    for (int i = 0; i < 4; ++i) {
      const int c = tid + i * 256;
      const int row = c >> 3, sl = c & 7;          // 8 slots of 16B per 64-elem row
      const int col = (sl ^ (row & 7)) * 8;        // pre-swizzle global source
      const uint32_t so = (uint32_t)row * DIN + k0 + col;
      gload_lds16(Whi + so, &As_hi[0][0] + c * 8);
      gload_lds16(Wlo + so, &As_lo[0][0] + c * 8);
    }
#pragma unroll
    for (int i = 0; i < 2; ++i) {
      const int c = tid + i * 256;
      const int row = c >> 3, sl = c & 7;
      const int col = (sl ^ (row & 7)) * 8;
      const uint32_t so = (uint32_t)(sblk * 64 + row) * DIN + k0 + col;
      gload_lds16(xhi + so, &Bs_hi[0][0] + c * 8);
      gload_lds16(xlo + so, &Bs_lo[0][0] + c * 8);
    }
  };
  auto COMPUTE = [&]() {
#pragma unroll
    for (int kk = 0; kk < 2; ++kk) {               // two 32-K halves of the chunk
      bf16x8 AH[4], AL[4], BH[2], BL[2];
#pragma unroll
      for (int mf = 0; mf < 4; ++mf) {
        const int row = wr * 64 + mf * 16 + c16;
        const int col = ((g + kk * 4) ^ (row & 7)) * 8;   // un-swizzle on read
        AH[mf] = ld8(&As_hi[row][col]);
        AL[mf] = ld8(&As_lo[row][col]);
      }
#pragma unroll
      for (int nf = 0; nf < 2; ++nf) {
        const int row = wc * 32 + nf * 16 + c16;
        const int col = ((g + kk * 4) ^ (row & 7)) * 8;
        BH[nf] = ld8(&Bs_hi[row][col]);
        BL[nf] = ld8(&Bs_lo[row][col]);
      }
#pragma unroll
      for (int mf = 0; mf < 4; ++mf)
#pragma unroll
        for (int nf = 0; nf < 2; ++nf) {
          acc[mf][nf] = mfma(AH[mf], BH[nf], acc[mf][nf]);   // hi*hi
          acc[mf][nf] = mfma(AH[mf], BL[nf], acc[mf][nf]);   // hi*lo
          acc[mf][nf] = mfma(AL[mf], BH[nf], acc[mf][nf]);   // lo*hi
        }
    }
  };

  for (int k0 = 0; k0 < DIN; k0 += 64) {           // m97 2-barrier loop
    __syncthreads();                               // prior compute done before overwrite
    STAGE(k0);
    __syncthreads();                               // compiler drains vmcnt before barrier
    COMPUTE();
  }

  if (proj < 2) {
    const float* bias = (proj == 0) ? bq : bk;
    uint16_t* ohi = (proj == 0) ? qhi : khi;
    uint16_t* olo = (proj == 0) ? qlo : klo;
#pragma unroll
    for (int mf = 0; mf < 4; ++mf) {
      const int d0 = wr * 64 + mf * 16 + g * 4;    // C^T row = d = 4g+r
      const float4 bs = *reinterpret_cast<const float4*>(bias + d0);
#pragma unroll
      for (int nf = 0; nf < 2; ++nf) {
        const int srow = sblk * 64 + wc * 32 + nf * 16 + c16;  // C^T col = s
        f32x4 v = acc[mf][nf];
        ushort4 h4, l4; uint16_t h, l;
        split2(v[0] + bs.x, h, l); h4.x = h; l4.x = l;
        split2(v[1] + bs.y, h, l); h4.y = h; l4.y = l;
        split2(v[2] + bs.z, h, l); h4.z = h; l4.z = l;
        split2(v[3] + bs.w, h, l); h4.w = h; l4.w = l;
        *reinterpret_cast<ushort4*>(ohi + (size_t)srow * DH + d0) = h4;
        *reinterpret_cast<ushort4*>(olo + (size_t)srow * DH + d0) = l4;
      }
    }
  } else {
    // V^T [b][d][s]: per lane 4 consecutive d-rows at fixed s -> 2B stores (32B runs).
#pragma unroll
    for (int mf = 0; mf < 4; ++mf) {
      const int d0 = wr * 64 + mf * 16 + g * 4;
      const float4 bs = *reinterpret_cast<const float4*>(bv + d0);
#pragma unroll
      for (int nf = 0; nf < 2; ++nf) {
        const int srow = sblk * 64 + wc * 32 + nf * 16 + c16;
        const int b = srow >> 11;
        const int sin = srow & (S_ - 1);
        f32x4 v = acc[mf][nf];
        vt[((size_t)b * DH + d0 + 0) * S_ + sin] = bf16_rne(v[0] + bs.x);
        vt[((size_t)b * DH + d0 + 1) * S_ + sin] = bf16_rne(v[1] + bs.y);
        vt[((size_t)b * DH + d0 + 2) * S_ + sin] = bf16_rne(v[2] + bs.z);
        vt[((size_t)b * DH + d0 + 3) * S_ + sin] = bf16_rne(v[3] + bs.w);
      }
    }
  }
}

// ---------- kernel 4: causal attention, K/V-shared flash block ----------
// Block = 4 waves = 4 CONSECUTIVE 16-row q-tiles {4g..4g+3} (q-rows 64g..64g+63):
// all four need exactly k-tiles 0..g (causally aligned), so K(hi/lo)+V are staged
// ONCE per block into double-buffered LDS (2x48KB) and shared by all waves.
// 2-phase loop: STAGE(t+1) issued before COMPUTE(t); one barrier per tile.
__global__ __launch_bounds__(256) void k_attn(
    const uint16_t* __restrict__ qhi, const uint16_t* __restrict__ qlo,
    const uint16_t* __restrict__ khi, const uint16_t* __restrict__ klo,
    const uint16_t* __restrict__ vt,
    const unsigned long long* __restrict__ bits,
    float* __restrict__ out) {
  __shared__ uint16_t Ks_hi[2][64][128];           // K tile hi  [s][d]  2x16KB
  __shared__ uint16_t Ks_lo[2][64][128];           // K tile lo  [s][d]  2x16KB
  __shared__ uint16_t Vs[2][128][64];              // V^T tile   [d][s]  2x16KB
  __shared__ uint16_t plds[4][16][72];             // per-wave P tile [q][k], +8 pad
  const int tid = threadIdx.x;
  const int wid = tid >> 6, lane = tid & 63;
  const int g = lane >> 4, c16 = lane & 15;
  const int b  = blockIdx.x & 7;
  const int gq = 31 - (blockIdx.x >> 3);           // q-group 0..31; big groups launch first
  const int q0 = gq * 64 + wid * 16;               // this wave's 16 q-rows
  const int qrow = q0 + c16;
  const int nt = gq + 1;                           // exact causal tile count, block-uniform

  const uint32_t qoff = (uint32_t)(b * S_ + qrow) * DH + g * 8;
  bf16x8 qH[4], qL[4];
#pragma unroll
  for (int c2 = 0; c2 < 4; ++c2) {
    qH[c2] = ld8(qhi + qoff + c2 * 32);
    qL[c2] = ld8(qlo + qoff + c2 * 32);
  }

  f32x4 acc[8] = {};                               // out^T frags: d=128, q=16
  float m_run = -1e30f, l_run = 0.0f;
  const uint32_t brow = (uint32_t)(b * S_ + qrow) * (S_ / 64);

  // stage k-tile t into buffer bi: K 64x128 (16 slots/row), V 128x64 (8 slots/row).
  // gload_lds dest is lane-linear; XOR-swizzle the GLOBAL source (involution).
  auto STAGE = [&](int t, int bi) {
    const int j0 = t * 64;
#pragma unroll
    for (int i = 0; i < 4; ++i) {
      const int c = tid + i * 256;                 // 1024 chunks of 16B
      const int r = c >> 4, p = c & 15;
      const int q = (p & 8) | ((p ^ r) & 7);
      const uint32_t so = (uint32_t)(b * S_ + j0 + r) * DH + q * 8;
      gload_lds16(khi + so, &Ks_hi[bi][0][0] + c * 8);
      gload_lds16(klo + so, &Ks_lo[bi][0][0] + c * 8);
    }
#pragma unroll
    for (int i = 0; i < 4; ++i) {
      const int c = tid + i * 256;                 // 1024 chunks of 16B
      const int r = c >> 3, p = c & 7;
      const int q = p ^ (r & 7);
      const uint32_t so = (uint32_t)(b * DH + r) * S_ + j0 + q * 8;
      gload_lds16(vt + so, &Vs[bi][0][0] + c * 8);
    }
  };

  STAGE(0, 0);
  for (int t = 0; t < nt; ++t) {
    __syncthreads();                               // drains vmcnt: stage(t) landed; buf safe
    if (t + 1 < nt) STAGE(t + 1, (t + 1) & 1);     // prefetch next tile (other buffer)
    const int bi = t & 1;
    const int j0 = t * 64;
    const unsigned long long bw = bits[brow + t];  // dropout bits, use is far below
    // S^T = K * Q^T   (split: hi*hi + hi*lo + lo*hi), K frags from LDS
    f32x4 st[4] = {};
#pragma unroll
    for (int kf = 0; kf < 4; ++kf) {
      const int r = kf * 16 + c16;
#pragma unroll
      for (int c2 = 0; c2 < 4; ++c2) {
        const int q = g + 4 * c2;                  // logical 16B slot
        const int p = (q & 8) | ((q ^ (r & 7)) & 7);
        const bf16x8 kH = ld8(&Ks_hi[bi][r][p * 8]);
        const bf16x8 kL = ld8(&Ks_lo[bi][r][p * 8]);
        st[kf] = mfma(kH, qH[c2], st[kf]);
        st[kf] = mfma(kH, qL[c2], st[kf]);
        st[kf] = mfma(kL, qH[c2], st[kf]);
      }
    }
    // causal + (wei==0 -> -inf) + row max (lane holds 16 k's of its q-row)
    float tmax = -INFINITY;
#pragma unroll
    for (int kf = 0; kf < 4; ++kf)
#pragma unroll
      for (int r = 0; r < 4; ++r) {
        const int kg = j0 + kf * 16 + g * 4 + r;   // C row = k
        float s = st[kf][r];
        s = (kg <= qrow && s != 0.0f) ? s : -INFINITY;
        st[kf][r] = s;
        tmax = fmaxf(tmax, s);
      }
    tmax = fmaxf(tmax, __shfl_xor(tmax, 16));
    tmax = fmaxf(tmax, __shfl_xor(tmax, 32));
    const float m_new = fmaxf(m_run, tmax);
    const float fs = __expf(m_run - m_new);
    m_run = m_new;
    float psum = 0.0f;
#pragma unroll
    for (int kf = 0; kf < 4; ++kf)
#pragma unroll
      for (int r = 0; r < 4; ++r) {
        const float pv = __expf(st[kf][r] - m_new);
        psum += pv;
        st[kf][r] = pv;
      }
    l_run = l_run * fs + psum;                     // denominator: no dropout
    // dropout via bits (bit -> *1.25 exactly matches the f32 mask), P -> bf16 -> LDS [q][k]
#pragma unroll
    for (int kf = 0; kf < 4; ++kf) {
      const int bi2 = kf * 16 + g * 4;
      ushort4 pb;
      pb.x = bf16_rne(((bw >> (bi2 + 0)) & 1ull) ? st[kf][0] * 1.25f : 0.0f);
      pb.y = bf16_rne(((bw >> (bi2 + 1)) & 1ull) ? st[kf][1] * 1.25f : 0.0f);
      pb.z = bf16_rne(((bw >> (bi2 + 2)) & 1ull) ? st[kf][2] * 1.25f : 0.0f);
      pb.w = bf16_rne(((bw >> (bi2 + 3)) & 1ull) ? st[kf][3] * 1.25f : 0.0f);
      *reinterpret_cast<ushort4*>(&plds[wid][c16][kf * 16 + g * 4]) = pb;
    }
#pragma unroll
    for (int mf = 0; mf < 8; ++mf) acc[mf] *= fs;  // rescale accumulator
    // PV: out^T += V^T * P^T, V frags from LDS
#pragma unroll
    for (int kc = 0; kc < 2; ++kc) {
      const bf16x8 pB = *reinterpret_cast<const bf16x8*>(&plds[wid][c16][kc * 32 + g * 8]);
#pragma unroll
      for (int mf = 0; mf < 8; ++mf) {
        const int r = mf * 16 + c16;
        const int q = kc * 4 + g;
        const int p = q ^ (r & 7);
        acc[mf] = mfma(ld8(&Vs[bi][r][p * 8]), pB, acc[mf]);
      }
    }
  }
  l_run += __shfl_xor(l_run, 16);
  l_run += __shfl_xor(l_run, 32);
  const float inv = 1.0f / l_run;
  const uint32_t orow = (uint32_t)(b * S_ + qrow) * DH;
#pragma unroll
  for (int mf = 0; mf < 8; ++mf) {
    float4 o;
    o.x = acc[mf][0] * inv;
    o.y = acc[mf][1] * inv;
    o.z = acc[mf][2] * inv;
    o.w = acc[mf][3] * inv;
    *reinterpret_cast<float4*>(out + orow + mf * 16 + g * 4) = o;   // row=d, col=q
  }
}

extern "C" void kernel_launch(void* const* d_in, const int* in_sizes, int n_in,
                              void* d_out, int out_size, void* d_ws, size_t ws_size,
                              hipStream_t stream) {
  const float* x    = (const float*)d_in[0];
  const float* Wq   = (const float*)d_in[1];
  const float* bq   = (const float*)d_in[2];
  const float* Wk   = (const float*)d_in[3];
  const float* bk   = (const float*)d_in[4];
  const float* Wv   = (const float*)d_in[5];
  const float* bv   = (const float*)d_in[6];
  const float* mask = (const float*)d_in[7];
  float* out = (float*)d_out;

  char* p = (char*)d_ws;
  auto take = [&](size_t bytes) {
    char* r = p;
    p += (bytes + 255) & ~(size_t)255;
    return r;
  };
  uint16_t* xhi  = (uint16_t*)take((size_t)M_ * DIN * 2);
  uint16_t* xlo  = (uint16_t*)take((size_t)M_ * DIN * 2);
  uint16_t* wthi = (uint16_t*)take((size_t)3 * DH * DIN * 2);
  uint16_t* wtlo = (uint16_t*)take((size_t)3 * DH * DIN * 2);
  uint16_t* qhi  = (uint16_t*)take((size_t)M_ * DH * 2);
  uint16_t* qlo  = (uint16_t*)take((size_t)M_ * DH * 2);
  uint16_t* khi  = (uint16_t*)take((size_t)M_ * DH * 2);
  uint16_t* klo  = (uint16_t*)take((size_t)M_ * DH * 2);
  uint16_t* vt   = (uint16_t*)take((size_t)M_ * DH * 2);
  unsigned long long* bits = (unsigned long long*)take((size_t)B_ * S_ * S_ / 8);

  k_split_x<<<2048, 256, 0, stream>>>(x, xhi, xlo, M_ * DIN / 4);
  k_mask_bits<<<2048, 256, 0, stream>>>(mask, bits, B_ * S_ * S_);
  k_split_wt<<<dim3(DH * DIN / 256, 3), 256, 0, stream>>>(Wq, Wk, Wv, wthi, wtlo);
  k_proj<<<dim3(M_ / 64, 3), 256, 0, stream>>>(xhi, xlo, wthi, wtlo, bq, bk, bv,
                                               qhi, qlo, khi, klo, vt);
  k_attn<<<256, 256, 0, stream>>>(qhi, qlo, khi, klo, vt, bits, out);
}